// Round 6
// baseline (4294.655 us; speedup 1.0000x reference)
//
#include <hip/hip_runtime.h>
#include <hip/hip_bf16.h>

// LSNN adaptive-LIF scan, T=1000, B=64, N_in=256, N_h=512, fp32.
//
// BITWISE CONSTRAINT (rounds 2-5): harness compares binary spikes exactly;
// flips cascade. numpy/OpenBLAS reduces k sequentially ascending, so the
// recurrent term for column n MUST be one serial ascending-index __fadd_rn
// chain over active neurons. No partial sums. Round 5 (passed, absmax 0.0)
// proves: sparse ascending chain + pad-with-+0.0 rows == BLAS bitwise.
//
// Round 6: issue-slot diet on the gather (the scan is issue-bound on the 64
// active CUs): paired-column float2 gather (1 addr add + 1 dwordx2 + 2 fadds
// per TWO columns), saddr-form addressing (uniform wT base in SGPRs),
// rec handoff to state threads via LDS recs[] under the existing B1/B2.

#define TT   1000
#define BB   64
#define NIN  256
#define NH   512
#define TSP  32                          // gather tile size in ROWS (pairs/thread)
#define PADOFF (NH * 2048)               // byte offset of zeroed row 512 of wT

__device__ constexpr float KV = (float)(0.001 * 100.0);            // DT*TAU_MEM_INV
__device__ constexpr float KI = (float)(0.001 * 200.0);            // DT*TAU_SYN_INV
__device__ constexpr float KB = (float)(0.001 * (1.0 / 800.0));    // DT*TAU_ADAPT_INV
__device__ constexpr float KJ = (float)((1.0 / 800.0) * 1.8);      // TAU_ADAPT_INV*BETA

// ---------------- transpose w_rec (512x512): wT[j][n] = w_rec[n][j] ----------
__global__ void transp512(const float* __restrict__ in, float* __restrict__ ot) {
    __shared__ float tile[32][33];
    const int tx = threadIdx.x;            // 0..31
    const int ty = threadIdx.y;            // 0..7
    const int jcol = blockIdx.x * 32 + tx;
    const int row0 = blockIdx.y * 32;
    for (int r = ty; r < 32; r += 8)
        tile[r][tx] = in[(size_t)(row0 + r) * NH + jcol];
    __syncthreads();
    const int ncol = blockIdx.y * 32 + tx;
    const int jrow0 = blockIdx.x * 32;
    for (int r = ty; r < 32; r += 8)
        ot[(size_t)(jrow0 + r) * NH + ncol] = tile[tx][r];
}

// zero row 512 of wT (padding target for unconditional gather tiles)
__global__ void zrow(float* __restrict__ wT) {
    wT[(size_t)NH * NH + threadIdx.x] = 0.0f;
}

// ---------------- fp32 GEMM: F[m][n] = sum_k X[m][k] * W[n][k] ---------------
// UNCHANGED from round 2 (bitwise-verified against the np reference).
__global__ __launch_bounds__(256)
void gemm_ff(const float* __restrict__ X, const float* __restrict__ W,
             float* __restrict__ F, int M) {
    const int bx = blockIdx.x;   // n-tile: 0..3
    const int by = blockIdx.y;   // m-tile
    const int tid = threadIdx.x;

    __shared__ float As[32][128];
    __shared__ float Bs[32][128];

    const int tn0 = (tid & 15) * 8;
    const int tm0 = (tid >> 4) * 8;
    float acc[8][8] = {};

    const int am = tid >> 1;
    const int aq = (tid & 1) * 4;

    const float* Xb = X + (size_t)(by * 128 + am) * NIN;
    const float* Wb = W + (size_t)(bx * 128 + am) * NIN;

    for (int k0 = 0; k0 < NIN; k0 += 32) {
        __syncthreads();
#pragma unroll
        for (int i2 = 0; i2 < 4; ++i2) {
            const int q = aq + i2;
            float4 xa = *reinterpret_cast<const float4*>(Xb + k0 + q * 4);
            As[q * 4 + 0][am] = xa.x; As[q * 4 + 1][am] = xa.y;
            As[q * 4 + 2][am] = xa.z; As[q * 4 + 3][am] = xa.w;
            float4 wa = *reinterpret_cast<const float4*>(Wb + k0 + q * 4);
            Bs[q * 4 + 0][am] = wa.x; Bs[q * 4 + 1][am] = wa.y;
            Bs[q * 4 + 2][am] = wa.z; Bs[q * 4 + 3][am] = wa.w;
        }
        __syncthreads();
#pragma unroll 8
        for (int kk = 0; kk < 32; ++kk) {
            float4 a0 = *reinterpret_cast<const float4*>(&As[kk][tm0]);
            float4 a1 = *reinterpret_cast<const float4*>(&As[kk][tm0 + 4]);
            float4 b0 = *reinterpret_cast<const float4*>(&Bs[kk][tn0]);
            float4 b1 = *reinterpret_cast<const float4*>(&Bs[kk][tn0 + 4]);
            const float av[8] = {a0.x, a0.y, a0.z, a0.w, a1.x, a1.y, a1.z, a1.w};
            const float bv[8] = {b0.x, b0.y, b0.z, b0.w, b1.x, b1.y, b1.z, b1.w};
#pragma unroll
            for (int i = 0; i < 8; ++i)
#pragma unroll
                for (int j = 0; j < 8; ++j)
                    acc[i][j] += av[i] * bv[j];
        }
    }

    float* Fo = F + (size_t)(by * 128 + tm0) * NH + bx * 128 + tn0;
#pragma unroll
    for (int i = 0; i < 8; ++i) {
        *reinterpret_cast<float4*>(Fo + (size_t)i * NH) =
            make_float4(acc[i][0], acc[i][1], acc[i][2], acc[i][3]);
        *reinterpret_cast<float4*>(Fo + (size_t)i * NH + 4) =
            make_float4(acc[i][4], acc[i][5], acc[i][6], acc[i][7]);
    }
}

// ---------------- paired gather tile helpers --------------------------------
// buf[i] = wT row (list offset) columns [2t, 2t+1]; saddr form: uniform base
// wb (SGPR) + 32-bit voffset (row byte offset + n8).
__device__ __forceinline__ void fill_tile2(float2 (&buf)[TSP], const int* lp,
                                           int base, const char* wb,
                                           unsigned n8) {
#pragma unroll
    for (int i = 0; i < TSP; i += 4) {
        const int4 o = *reinterpret_cast<const int4*>(lp + base + i);
        buf[i + 0] = *reinterpret_cast<const float2*>(wb + (unsigned)(o.x + (int)n8));
        buf[i + 1] = *reinterpret_cast<const float2*>(wb + (unsigned)(o.y + (int)n8));
        buf[i + 2] = *reinterpret_cast<const float2*>(wb + (unsigned)(o.z + (int)n8));
        buf[i + 3] = *reinterpret_cast<const float2*>(wb + (unsigned)(o.w + (int)n8));
    }
}
__device__ __forceinline__ void add_tile2(const float2 (&buf)[TSP],
                                          float& r0, float& r1) {
#pragma unroll
    for (int i = 0; i < TSP; ++i) {
        r0 = __fadd_rn(r0, buf[i].x);   // column 2t chain
        r1 = __fadd_rn(r1, buf[i].y);   // column 2t+1 chain (independent)
    }
}

// ---------------- scan kernel: one WG (512 thr) per batch element -----------
// st layout: [z | v | i | b], each BB*NH floats.
__global__ __launch_bounds__(512, 2)
void lsnn_scan(const float* __restrict__ F, const float* __restrict__ wT,
               const float* __restrict__ z0, const float* __restrict__ v0,
               const float* __restrict__ i0, const float* __restrict__ b0,
               float* __restrict__ out, float* __restrict__ st,
               int t0, int Tc, int first, int last) {
    const int n    = threadIdx.x;        // neuron / column 0..511
    const int b    = blockIdx.x;         // batch
    const int lane = n & 63;
    const int wv   = n >> 6;             // wave 0..7
    const bool gth = (n < 256);          // gather thread: columns 2n, 2n+1
    const size_t bn = (size_t)b * NH + n;

    __shared__ __align__(16) int lists[2][NH + 2 * TSP];  // row byte offsets + pad
    __shared__ int cnts[2][8];
    __shared__ __align__(8) float recs[NH];

    float v, cur, bb, zprev;
    if (first) {
        zprev = z0[bn]; v = v0[bn]; cur = i0[bn]; bb = b0[bn];
    } else {
        zprev = st[0 * BB * NH + bn];
        v     = st[1 * BB * NH + bn];
        cur   = st[2 * BB * NH + bn];
        bb    = st[3 * BB * NH + bn];
    }

    // ---- initial list build (buffer 0), ascending neuron order -------------
    int cnt;
    {
        const unsigned long long m = __ballot(zprev > 0.0f);
        if (lane == 0) cnts[0][wv] = __popcll(m);
        __syncthreads();
        int base = 0, tot = 0;
        for (int q = 0; q < 8; ++q) {
            const int c = cnts[0][q];
            if (q < wv) base += c;
            tot += c;
        }
        if (zprev > 0.0f)
            lists[0][base + __popcll(m & ((1ull << lane) - 1ull))] = n << 11;
        if (n < 2 * TSP) lists[0][tot + n] = PADOFF;   // pad region
        __syncthreads();
        cnt = tot;
    }
    int par = 0;

    const char*  wb = reinterpret_cast<const char*>(wT);   // uniform base (SGPR)
    const unsigned n8 = (unsigned)n * 8u;                  // gth column-pair byte off
    const float* Fp = F + (size_t)b * NH + n;
    float* op = out + ((size_t)t0 * BB + b) * NH + n;

    for (int t = 0; t < Tc; ++t) {
        // ---- t.1: prefetch F, elementwise update, ballot --------------------
        const float fval = Fp[(size_t)t * BB * NH];   // consumed in t.3
        const float v_dec = __fadd_rn(v, __fmul_rn(KV, __fadd_rn(__fsub_rn(0.0f, v), cur)));
        const float i_dec = __fsub_rn(cur, __fmul_rn(KI, cur));
        const float b_dec = __fadd_rn(bb, __fmul_rn(KB, __fsub_rn(1.0f, bb)));
        const float zn = (__fsub_rn(v_dec, b_dec) > 0.0f) ? 1.0f : 0.0f;
        v  = (zn > 0.0f) ? 0.0f : v_dec;
        bb = __fadd_rn(b_dec, __fmul_rn(zn, KJ));
        op[0] = zn;
        op += (size_t)BB * NH;
        const unsigned long long mm = __ballot(zn > 0.0f);
        if (lane == 0) cnts[par ^ 1][wv] = __popcll(mm);

        // ---- t.2: pipelined serial gather over lists[par] (threads 0-255) ---
        // Two independent ascending __fadd_rn chains per thread (cols 2n,2n+1).
        if (gth) {
            float r0 = 0.0f, r1 = 0.0f;
            if (cnt > 0) {
                const int* lp = lists[par];
                float2 bufA[TSP], bufB[TSP];
                fill_tile2(bufA, lp, 0, wb, n8);
                int kt = 0;
                for (;;) {
                    fill_tile2(bufB, lp, kt + TSP, wb, n8);
                    add_tile2(bufA, r0, r1);
                    kt += TSP;
                    if (kt >= cnt) break;
                    fill_tile2(bufA, lp, kt + TSP, wb, n8);
                    add_tile2(bufB, r0, r1);
                    kt += TSP;
                    if (kt >= cnt) break;
                }
            }
            *reinterpret_cast<float2*>(&recs[n << 1]) = make_float2(r0, r1);
        }

        __syncthreads();   // B1: recs + cnts[par^1] published; lists[par] drained

        // ---- t.3: combine, update cur; build next list (lists[par^1]) -------
        cur = __fadd_rn(__fadd_rn(i_dec, fval), recs[n]);
        zprev = zn;
        int base = 0, tot = 0;
        for (int q = 0; q < 8; ++q) {
            const int c = cnts[par ^ 1][q];
            if (q < wv) base += c;
            tot += c;
        }
        if (zn > 0.0f)
            lists[par ^ 1][base + __popcll(mm & ((1ull << lane) - 1ull))] = n << 11;
        if (n < 2 * TSP) lists[par ^ 1][tot + n] = PADOFF;
        __syncthreads();   // B2: lists[par^1] ready; recs drained

        par ^= 1;
        cnt = tot;
    }

    st[0 * BB * NH + bn] = zprev;
    st[1 * BB * NH + bn] = v;
    st[2 * BB * NH + bn] = cur;
    st[3 * BB * NH + bn] = bb;
    if (last) {
        float* tail = out + (size_t)TT * BB * NH;
        tail[0 * BB * NH + bn] = zprev;  // zT
        tail[1 * BB * NH + bn] = v;      // vT
        tail[2 * BB * NH + bn] = cur;    // iT
        tail[3 * BB * NH + bn] = bb;     // bT
    }
}

// ---------------------------------------------------------------------------
extern "C" void kernel_launch(void* const* d_in, const int* in_sizes, int n_in,
                              void* d_out, int out_size, void* d_ws, size_t ws_size,
                              hipStream_t stream) {
    const float* X     = (const float*)d_in[0];
    const float* z0    = (const float*)d_in[1];
    const float* v0    = (const float*)d_in[2];
    const float* i0    = (const float*)d_in[3];
    const float* b0    = (const float*)d_in[4];
    const float* w_in  = (const float*)d_in[5];
    const float* w_rec = (const float*)d_in[6];
    float* out = (float*)d_out;

    char* ws = (char*)d_ws;
    float* wT = (float*)ws;                                    // 1 MB + zero row
    const size_t wT_bytes = ((size_t)NH * NH + NH) * 4 + 2048;
    float* st = (float*)(ws + wT_bytes);                       // 512 KB
    char*  fbase = ws + wT_bytes + (512u << 10);

    const long long per = (long long)BB * NH * 4;              // bytes/step of F
    long long avail = (long long)ws_size - (long long)(wT_bytes + (512u << 10));
    int Tc;
    if (avail >= 2 * per * TT) {
        Tc = TT;
    } else {
        Tc = (int)(avail / (2 * per));
        if (Tc > TT) Tc = TT;
        Tc &= ~1;
        if (Tc < 2) Tc = 2;
    }
    const size_t fbytes = (size_t)Tc * per;
    float* Fb[2] = { (float*)fbase, (float*)(fbase + fbytes) };

    transp512<<<dim3(16, 16), dim3(32, 8), 0, stream>>>(w_rec, wT);
    zrow<<<1, NH, 0, stream>>>(wT);

    int t0 = 0, buf = 0;
    bool firstc = true;
    while (t0 < TT) {
        const int Tcur = (Tc < TT - t0) ? Tc : (TT - t0);
        const int Mc = Tcur * BB;
        gemm_ff<<<dim3(4, Mc / 128), 256, 0, stream>>>(
            X + (size_t)t0 * BB * NIN, w_in, Fb[buf], Mc);
        lsnn_scan<<<dim3(BB), dim3(512), 0, stream>>>(
            Fb[buf], wT, z0, v0, i0, b0, out, st,
            t0, Tcur, firstc ? 1 : 0, (t0 + Tcur >= TT) ? 1 : 0);
        firstc = false;
        buf ^= 1;
        t0 += Tcur;
    }
}

// Round 7
// 2721.765 us; speedup vs baseline: 1.5779x; 1.5779x over previous
//
#include <hip/hip_runtime.h>
#include <hip/hip_bf16.h>

// LSNN adaptive-LIF scan, T=1000, B=64, N_in=256, N_h=512, fp32.
//
// BITWISE CONSTRAINT (rounds 2-5): harness compares binary spikes exactly;
// flips cascade. numpy/OpenBLAS reduces k sequentially ascending, so the
// recurrent term for column n MUST be one serial ascending-index __fadd_rn
// chain over active neurons. No partial sums. Rounds 2/5 (passed, absmax 0)
// prove: sparse ascending chain + pad-with-+0.0 rows == BLAS bitwise.
//
// Round 7: the diagnosed bottleneck is exposed L2 latency — hipcc sinks
// gather loads to their uses (r5/r6 VGPR=56/52 prove the register tiles
// were never materialized; ~cnt/4 x ~200cy = measured step time). Fix:
// round-5 structure (512 thr, 1 col/thread, 8 gather waves = 2/SIMD) with
// 16-element double-buffered tiles and __builtin_amdgcn_sched_barrier(0)
// after each fill, pinning 16 loads in flight above the previous tile's
// add chain (auto-waitcnt becomes vmcnt(16), not vmcnt(0)).

#define TT   1000
#define BB   64
#define NIN  256
#define NH   512
#define TS   16                          // gather tile size
#define PADOFF (NH * 2048)               // byte offset of zeroed row 512 of wT

__device__ constexpr float KV = (float)(0.001 * 100.0);            // DT*TAU_MEM_INV
__device__ constexpr float KI = (float)(0.001 * 200.0);            // DT*TAU_SYN_INV
__device__ constexpr float KB = (float)(0.001 * (1.0 / 800.0));    // DT*TAU_ADAPT_INV
__device__ constexpr float KJ = (float)((1.0 / 800.0) * 1.8);      // TAU_ADAPT_INV*BETA

// ---------------- transpose w_rec (512x512): wT[j][n] = w_rec[n][j] ----------
__global__ void transp512(const float* __restrict__ in, float* __restrict__ ot) {
    __shared__ float tile[32][33];
    const int tx = threadIdx.x;            // 0..31
    const int ty = threadIdx.y;            // 0..7
    const int jcol = blockIdx.x * 32 + tx;
    const int row0 = blockIdx.y * 32;
    for (int r = ty; r < 32; r += 8)
        tile[r][tx] = in[(size_t)(row0 + r) * NH + jcol];
    __syncthreads();
    const int ncol = blockIdx.y * 32 + tx;
    const int jrow0 = blockIdx.x * 32;
    for (int r = ty; r < 32; r += 8)
        ot[(size_t)(jrow0 + r) * NH + ncol] = tile[tx][r];
}

// zero row 512 of wT (padding target for unconditional gather tiles)
__global__ void zrow(float* __restrict__ wT) {
    wT[(size_t)NH * NH + threadIdx.x] = 0.0f;
}

// ---------------- fp32 GEMM: F[m][n] = sum_k X[m][k] * W[n][k] ---------------
// UNCHANGED from round 2 (bitwise-verified against the np reference).
__global__ __launch_bounds__(256)
void gemm_ff(const float* __restrict__ X, const float* __restrict__ W,
             float* __restrict__ F, int M) {
    const int bx = blockIdx.x;   // n-tile: 0..3
    const int by = blockIdx.y;   // m-tile
    const int tid = threadIdx.x;

    __shared__ float As[32][128];
    __shared__ float Bs[32][128];

    const int tn0 = (tid & 15) * 8;
    const int tm0 = (tid >> 4) * 8;
    float acc[8][8] = {};

    const int am = tid >> 1;
    const int aq = (tid & 1) * 4;

    const float* Xb = X + (size_t)(by * 128 + am) * NIN;
    const float* Wb = W + (size_t)(bx * 128 + am) * NIN;

    for (int k0 = 0; k0 < NIN; k0 += 32) {
        __syncthreads();
#pragma unroll
        for (int i2 = 0; i2 < 4; ++i2) {
            const int q = aq + i2;
            float4 xa = *reinterpret_cast<const float4*>(Xb + k0 + q * 4);
            As[q * 4 + 0][am] = xa.x; As[q * 4 + 1][am] = xa.y;
            As[q * 4 + 2][am] = xa.z; As[q * 4 + 3][am] = xa.w;
            float4 wa = *reinterpret_cast<const float4*>(Wb + k0 + q * 4);
            Bs[q * 4 + 0][am] = wa.x; Bs[q * 4 + 1][am] = wa.y;
            Bs[q * 4 + 2][am] = wa.z; Bs[q * 4 + 3][am] = wa.w;
        }
        __syncthreads();
#pragma unroll 8
        for (int kk = 0; kk < 32; ++kk) {
            float4 a0 = *reinterpret_cast<const float4*>(&As[kk][tm0]);
            float4 a1 = *reinterpret_cast<const float4*>(&As[kk][tm0 + 4]);
            float4 b0 = *reinterpret_cast<const float4*>(&Bs[kk][tn0]);
            float4 b1 = *reinterpret_cast<const float4*>(&Bs[kk][tn0 + 4]);
            const float av[8] = {a0.x, a0.y, a0.z, a0.w, a1.x, a1.y, a1.z, a1.w};
            const float bv[8] = {b0.x, b0.y, b0.z, b0.w, b1.x, b1.y, b1.z, b1.w};
#pragma unroll
            for (int i = 0; i < 8; ++i)
#pragma unroll
                for (int j = 0; j < 8; ++j)
                    acc[i][j] += av[i] * bv[j];
        }
    }

    float* Fo = F + (size_t)(by * 128 + tm0) * NH + bx * 128 + tn0;
#pragma unroll
    for (int i = 0; i < 8; ++i) {
        *reinterpret_cast<float4*>(Fo + (size_t)i * NH) =
            make_float4(acc[i][0], acc[i][1], acc[i][2], acc[i][3]);
        *reinterpret_cast<float4*>(Fo + (size_t)i * NH + 4) =
            make_float4(acc[i][4], acc[i][5], acc[i][6], acc[i][7]);
    }
}

// ---------------- gather tile helpers ---------------------------------------
// Loads are pinned ahead of the consuming chain by sched_barrier(0) at the
// call sites. Offsets read from LDS as int4 (ds_read_b128), address = uniform
// SGPR base + (row byte offset + column byte offset).
__device__ __forceinline__ void fill_tile(float (&buf)[TS], const int* lp,
                                          int base, const char* wb,
                                          unsigned n4) {
#pragma unroll
    for (int i = 0; i < TS; i += 4) {
        const int4 o = *reinterpret_cast<const int4*>(lp + base + i);
        buf[i + 0] = *reinterpret_cast<const float*>(wb + (unsigned)(o.x + (int)n4));
        buf[i + 1] = *reinterpret_cast<const float*>(wb + (unsigned)(o.y + (int)n4));
        buf[i + 2] = *reinterpret_cast<const float*>(wb + (unsigned)(o.z + (int)n4));
        buf[i + 3] = *reinterpret_cast<const float*>(wb + (unsigned)(o.w + (int)n4));
    }
}
__device__ __forceinline__ void add_tile(const float (&buf)[TS], float& rec) {
#pragma unroll
    for (int i = 0; i < TS; ++i) rec = __fadd_rn(rec, buf[i]);
}

// ---------------- scan kernel: one WG (512 thr) per batch element -----------
// st layout: [z | v | i | b], each BB*NH floats.
__global__ __launch_bounds__(512, 1)
void lsnn_scan(const float* __restrict__ F, const float* __restrict__ wT,
               const float* __restrict__ z0, const float* __restrict__ v0,
               const float* __restrict__ i0, const float* __restrict__ b0,
               float* __restrict__ out, float* __restrict__ st,
               int t0, int Tc, int first, int last) {
    const int n    = threadIdx.x;        // neuron / column 0..511
    const int b    = blockIdx.x;         // batch
    const int lane = n & 63;
    const int wv   = n >> 6;             // wave 0..7
    const size_t bn = (size_t)b * NH + n;

    __shared__ __align__(16) int lists[2][NH + 2 * TS];  // row byte offsets + pad
    __shared__ int cnts[2][8];

    float v, cur, bb, zprev;
    if (first) {
        zprev = z0[bn]; v = v0[bn]; cur = i0[bn]; bb = b0[bn];
    } else {
        zprev = st[0 * BB * NH + bn];
        v     = st[1 * BB * NH + bn];
        cur   = st[2 * BB * NH + bn];
        bb    = st[3 * BB * NH + bn];
    }

    // ---- initial list build (buffer 0), ascending neuron order -------------
    int cnt;
    {
        const unsigned long long m = __ballot(zprev > 0.0f);
        if (lane == 0) cnts[0][wv] = __popcll(m);
        __syncthreads();
        int base = 0, tot = 0;
        for (int q = 0; q < 8; ++q) {
            const int c = cnts[0][q];
            if (q < wv) base += c;
            tot += c;
        }
        if (zprev > 0.0f)
            lists[0][base + __popcll(m & ((1ull << lane) - 1ull))] = n << 11;
        if (n < 2 * TS) lists[0][tot + n] = PADOFF;   // pad region
        __syncthreads();
        cnt = tot;
    }
    int par = 0;

    const char*  wb = reinterpret_cast<const char*>(wT);   // uniform base (SGPR)
    const unsigned n4 = (unsigned)n * 4u;                  // column byte offset
    const float* Fp = F + (size_t)b * NH + n;
    float* op = out + ((size_t)t0 * BB + b) * NH + n;

    for (int t = 0; t < Tc; ++t) {
        // ---- t.1: prefetch F, elementwise update, ballot --------------------
        const float fval = Fp[(size_t)t * BB * NH];   // consumed after gather
        const float v_dec = __fadd_rn(v, __fmul_rn(KV, __fadd_rn(__fsub_rn(0.0f, v), cur)));
        const float i_dec = __fsub_rn(cur, __fmul_rn(KI, cur));
        const float b_dec = __fadd_rn(bb, __fmul_rn(KB, __fsub_rn(1.0f, bb)));
        const float zn = (__fsub_rn(v_dec, b_dec) > 0.0f) ? 1.0f : 0.0f;
        v  = (zn > 0.0f) ? 0.0f : v_dec;
        bb = __fadd_rn(b_dec, __fmul_rn(zn, KJ));
        op[0] = zn;
        op += (size_t)BB * NH;
        const unsigned long long mm = __ballot(zn > 0.0f);
        if (lane == 0) cnts[par ^ 1][wv] = __popcll(mm);

        // ---- t.2: pipelined serial gather over lists[par] -------------------
        // One ascending __fadd_rn chain per column (bitwise == BLAS).
        // sched_barrier(0) after each fill pins the tile's 16 loads ahead of
        // the previous tile's add chain -> auto-waitcnt vmcnt(16), not 0.
        float rec = 0.0f;
        if (cnt > 0) {
            const int* lp = lists[par];
            float bufA[TS], bufB[TS];
            fill_tile(bufA, lp, 0, wb, n4);
            __builtin_amdgcn_sched_barrier(0);
            int kt = 0;
            for (;;) {
                fill_tile(bufB, lp, kt + TS, wb, n4);   // next tile in flight
                __builtin_amdgcn_sched_barrier(0);
                add_tile(bufA, rec);                    // chain current tile
                kt += TS;
                if (kt >= cnt) break;
                fill_tile(bufA, lp, kt + TS, wb, n4);
                __builtin_amdgcn_sched_barrier(0);
                add_tile(bufB, rec);
                kt += TS;
                if (kt >= cnt) break;
            }
        }
        cur = __fadd_rn(__fadd_rn(i_dec, fval), rec);
        zprev = zn;

        __syncthreads();   // B1: cnts[par^1] published; lists[par] drained

        // ---- t.3: build next list (lists[par^1]) ----------------------------
        int base = 0, tot = 0;
        for (int q = 0; q < 8; ++q) {
            const int c = cnts[par ^ 1][q];
            if (q < wv) base += c;
            tot += c;
        }
        if (zn > 0.0f)
            lists[par ^ 1][base + __popcll(mm & ((1ull << lane) - 1ull))] = n << 11;
        if (n < 2 * TS) lists[par ^ 1][tot + n] = PADOFF;
        __syncthreads();   // B2: lists[par^1] ready

        par ^= 1;
        cnt = tot;
    }

    st[0 * BB * NH + bn] = zprev;
    st[1 * BB * NH + bn] = v;
    st[2 * BB * NH + bn] = cur;
    st[3 * BB * NH + bn] = bb;
    if (last) {
        float* tail = out + (size_t)TT * BB * NH;
        tail[0 * BB * NH + bn] = zprev;  // zT
        tail[1 * BB * NH + bn] = v;      // vT
        tail[2 * BB * NH + bn] = cur;    // iT
        tail[3 * BB * NH + bn] = bb;     // bT
    }
}

// ---------------------------------------------------------------------------
extern "C" void kernel_launch(void* const* d_in, const int* in_sizes, int n_in,
                              void* d_out, int out_size, void* d_ws, size_t ws_size,
                              hipStream_t stream) {
    const float* X     = (const float*)d_in[0];
    const float* z0    = (const float*)d_in[1];
    const float* v0    = (const float*)d_in[2];
    const float* i0    = (const float*)d_in[3];
    const float* b0    = (const float*)d_in[4];
    const float* w_in  = (const float*)d_in[5];
    const float* w_rec = (const float*)d_in[6];
    float* out = (float*)d_out;

    char* ws = (char*)d_ws;
    float* wT = (float*)ws;                                    // 1 MB + zero row
    const size_t wT_bytes = ((size_t)NH * NH + NH) * 4 + 2048;
    float* st = (float*)(ws + wT_bytes);                       // 512 KB
    char*  fbase = ws + wT_bytes + (512u << 10);

    const long long per = (long long)BB * NH * 4;              // bytes/step of F
    long long avail = (long long)ws_size - (long long)(wT_bytes + (512u << 10));
    int Tc;
    if (avail >= 2 * per * TT) {
        Tc = TT;
    } else {
        Tc = (int)(avail / (2 * per));
        if (Tc > TT) Tc = TT;
        Tc &= ~1;
        if (Tc < 2) Tc = 2;
    }
    const size_t fbytes = (size_t)Tc * per;
    float* Fb[2] = { (float*)fbase, (float*)(fbase + fbytes) };

    transp512<<<dim3(16, 16), dim3(32, 8), 0, stream>>>(w_rec, wT);
    zrow<<<1, NH, 0, stream>>>(wT);

    int t0 = 0, buf = 0;
    bool firstc = true;
    while (t0 < TT) {
        const int Tcur = (Tc < TT - t0) ? Tc : (TT - t0);
        const int Mc = Tcur * BB;
        gemm_ff<<<dim3(4, Mc / 128), 256, 0, stream>>>(
            X + (size_t)t0 * BB * NIN, w_in, Fb[buf], Mc);
        lsnn_scan<<<dim3(BB), dim3(512), 0, stream>>>(
            Fb[buf], wT, z0, v0, i0, b0, out, st,
            t0, Tcur, firstc ? 1 : 0, (t0 + Tcur >= TT) ? 1 : 0);
        firstc = false;
        buf ^= 1;
        t0 += Tcur;
    }
}